// Round 2
// baseline (370.883 us; speedup 1.0000x reference)
//
#include <hip/hip_runtime.h>
#include <hip/hip_bf16.h>

// MaskedAttentionLayer: B=4, N=4096, D=256, fp32 in/out.
// Quirks honored: mask keeps strictly-future (m>n); softmax over the QUERY
// axis (per-column normalization). O = E @ (V/colsum) with E = exp(S), no
// max-subtraction needed (scores bounded); column m=0 fully masked ->
// uniform 1/4096 handled as epilogue constant V[b,0,:]/4096.

typedef float f32x4 __attribute__((ext_vector_type(4)));
typedef __bf16 bf16x8 __attribute__((ext_vector_type(8)));
typedef __bf16 bf16x4 __attribute__((ext_vector_type(4)));

#define MFMA16(a, b, c) __builtin_amdgcn_mfma_f32_16x16x32_bf16((a), (b), (c), 0, 0, 0)

constexpr int SEQ = 4096;
constexpr int DIM = 256;

// ---------------------------------------------------------------- k_prep
__global__ void k_prep(const float* __restrict__ Wq, const float* __restrict__ Wk,
                       const float* __restrict__ Wv, __bf16* __restrict__ Wb,
                       float* __restrict__ colsum) {
  int i = blockIdx.x * 256 + threadIdx.x;
  if (i < 3 * 65536) {
    const float* src = (i < 65536) ? Wq : (i < 131072 ? Wk : Wv);
    Wb[i] = (__bf16)src[i & 65535];
  }
  if (i < 4 * SEQ) colsum[i] = 0.f;
}

// ---------------------------------------------------------------- k_qkv
// C[i,j] = sum_d x[i,d] * W[j,d]   (i over B*N=16384, j over 256)
__global__ __launch_bounds__(256, 1) void k_qkv(const float* __restrict__ x,
                                                const __bf16* __restrict__ Wb,
                                                __bf16* __restrict__ Qb,
                                                __bf16* __restrict__ Kb,
                                                __bf16* __restrict__ Vb) {
  __shared__ __bf16 xs[128][40];
  __shared__ __bf16 wsh[64][40];
  const int t = threadIdx.x, lane = t & 63, w = t >> 6;
  const int wi = w >> 1, wj = w & 1;
  const int ln = lane & 15, quad = lane >> 4, q8 = quad * 8;
  const int i0 = blockIdx.x * 128;
  const int j0 = blockIdx.y * 64;
  const __bf16* W = Wb + blockIdx.z * 65536;
  __bf16* Out = (blockIdx.z == 0) ? Qb : (blockIdx.z == 1 ? Kb : Vb);
  f32x4 acc[4][2] = {};
  for (int dk = 0; dk < 8; ++dk) {
    __syncthreads();
#pragma unroll
    for (int v = 0; v < 4; ++v) {
      int f = t + v * 256;
      int row = f >> 3, c4 = f & 7;
      float4 val = *(const float4*)&x[(size_t)(i0 + row) * DIM + dk * 32 + c4 * 4];
      bf16x4 bv = {(__bf16)val.x, (__bf16)val.y, (__bf16)val.z, (__bf16)val.w};
      *(bf16x4*)&xs[row][c4 * 4] = bv;
    }
    {
      int row = t >> 2, c = t & 3;
      *(bf16x8*)&wsh[row][c * 8] =
          *(const bf16x8*)&W[(size_t)(j0 + row) * DIM + dk * 32 + c * 8];
    }
    __syncthreads();
    bf16x8 bb[2];
#pragma unroll
    for (int tj = 0; tj < 2; ++tj)
      bb[tj] = *(bf16x8*)&wsh[wj * 32 + tj * 16 + ln][q8];
#pragma unroll
    for (int ti = 0; ti < 4; ++ti) {
      bf16x8 a = *(bf16x8*)&xs[wi * 64 + ti * 16 + ln][q8];
#pragma unroll
      for (int tj = 0; tj < 2; ++tj)
        acc[ti][tj] = MFMA16(a, bb[tj], acc[ti][tj]);
    }
  }
#pragma unroll
  for (int ti = 0; ti < 4; ++ti)
#pragma unroll
    for (int tj = 0; tj < 2; ++tj)
#pragma unroll
      for (int r = 0; r < 4; ++r) {
        int row = i0 + wi * 64 + ti * 16 + quad * 4 + r;
        int col = j0 + wj * 32 + tj * 16 + ln;
        Out[(size_t)row * DIM + col] = (__bf16)acc[ti][tj][r];
      }
}

// ---------------------------------------------------------------- k_colsum
// colsum[b,m] = sum_{n<m} exp(q_n . k_m / 16).  Early-exits fully-masked
// regions (n >= m): ~2x less work than full S.
__global__ __launch_bounds__(256, 1) void k_colsum(const __bf16* __restrict__ Qb,
                                                   const __bf16* __restrict__ Kb,
                                                   float* __restrict__ colsum) {
  __shared__ __bf16 ksh[128][136];
  __shared__ __bf16 qs[64][136];
  const int t = threadIdx.x, lane = t & 63, w = t >> 6;
  const int ln = lane & 15, quad = lane >> 4, q8 = quad * 8;
  const int b = blockIdx.z;
  const int m0 = blockIdx.x * 128;
  const int nbase = blockIdx.y * 512;
  if (nbase > m0 + 126) return;  // no n < m possible in this block
  const __bf16* Qp = Qb + (size_t)b * SEQ * DIM;
  const __bf16* Kp = Kb + (size_t)b * SEQ * DIM;
  float partial[2] = {0.f, 0.f};
  for (int ns = 0; ns < 8; ++ns) {
    if (nbase + ns * 64 > m0 + 126) break;  // all later chunks masked too
    f32x4 acc[4][2] = {};
    for (int h = 0; h < 2; ++h) {
      __syncthreads();
      {
        int row = t >> 2, part = t & 3;
        const __bf16* src = &Qp[(size_t)(nbase + ns * 64 + row) * DIM + h * 128 + part * 32];
#pragma unroll
        for (int i = 0; i < 4; ++i)
          *(bf16x8*)&qs[row][part * 32 + i * 8] = *(const bf16x8*)&src[i * 8];
      }
      {
        int row = t >> 1, part = t & 1;
        const __bf16* src = &Kp[(size_t)(m0 + row) * DIM + h * 128 + part * 64];
#pragma unroll
        for (int i = 0; i < 8; ++i)
          *(bf16x8*)&ksh[row][part * 64 + i * 8] = *(const bf16x8*)&src[i * 8];
      }
      __syncthreads();
#pragma unroll
      for (int kf = 0; kf < 4; ++kf) {
        bf16x8 bb[2];
#pragma unroll
        for (int tm = 0; tm < 2; ++tm)
          bb[tm] = *(bf16x8*)&ksh[w * 32 + tm * 16 + ln][kf * 32 + q8];
#pragma unroll
        for (int tn = 0; tn < 4; ++tn) {
          bf16x8 a = *(bf16x8*)&qs[tn * 16 + ln][kf * 32 + q8];
#pragma unroll
          for (int tm = 0; tm < 2; ++tm)
            acc[tn][tm] = MFMA16(a, bb[tm], acc[tn][tm]);
        }
      }
    }
#pragma unroll
    for (int tn = 0; tn < 4; ++tn)
#pragma unroll
      for (int tm = 0; tm < 2; ++tm)
#pragma unroll
        for (int r = 0; r < 4; ++r) {
          int n_g = nbase + ns * 64 + tn * 16 + quad * 4 + r;
          int m_g = m0 + w * 32 + tm * 16 + ln;
          float e = (n_g < m_g) ? __expf(acc[tn][tm][r] * 0.0625f) : 0.f;
          partial[tm] += e;
        }
  }
#pragma unroll
  for (int tm = 0; tm < 2; ++tm) {
    float v = partial[tm];
    v += __shfl_xor(v, 16);
    v += __shfl_xor(v, 32);
    if (quad == 0)
      atomicAdd(&colsum[b * SEQ + m0 + w * 32 + tm * 16 + ln], v);
  }
}

// ---------------------------------------------------------------- k_vpt
// VpT[b][d][m] = V[b][m][d] / colsum[b][m]
__global__ void k_vpt(const __bf16* __restrict__ Vb, const float* __restrict__ colsum,
                      __bf16* __restrict__ VpT) {
  __shared__ __bf16 tile[64][72];
  const int t = threadIdx.x;
  const int b = blockIdx.z;
  const int m0 = blockIdx.x * 64, d0 = blockIdx.y * 64;
  {
    int row = t >> 2, part = t & 3;
    float cs = colsum[b * SEQ + m0 + row];
    float inv = (m0 + row == 0) ? (1.0f / 4096.0f) : (1.0f / cs);
#pragma unroll
    for (int i = 0; i < 2; ++i) {
      int c = part * 2 + i;
      bf16x8 v = *(const bf16x8*)&Vb[(size_t)(b * SEQ + m0 + row) * DIM + d0 + c * 8];
      bf16x8 o;
#pragma unroll
      for (int j = 0; j < 8; ++j) o[j] = (__bf16)((float)v[j] * inv);
      *(bf16x8*)&tile[row][c * 8] = o;
    }
  }
  __syncthreads();
  {
    int row = t >> 2, part = t & 3;
#pragma unroll
    for (int i = 0; i < 2; ++i) {
      int c = part * 2 + i;
      bf16x8 o;
#pragma unroll
      for (int j = 0; j < 8; ++j) o[j] = tile[c * 8 + j][row];
      *(bf16x8*)&VpT[(size_t)(b * DIM + d0 + row) * SEQ + m0 + c * 8] = o;
    }
  }
}

// ---------------------------------------------------------------- k_attn v2
// O[b, n0..n0+31, :] = sum_{m>n} E[n,m] * VpT[:,m]  + V[b,0,:]/4096.
// 512 blocks (2/CU), 512 threads. No K/V LDS staging: B-operand fragments
// for QK^T (K rows) and PV (VpT rows) are 16B-contiguous in global and
// L2-hot (K+VpT per batch = 4MB = one XCD L2). LDS = Q tile + P round-trip
// (~25 KB). S-phase: wave w owns m-cols [w*16,w*16+16). PV: wave w owns
// d-cols [w*32,w*32+32). Heavy tiles (small nt) launch first.
__global__ __launch_bounds__(512, 4) void k_attn(const __bf16* __restrict__ Qb,
                                                 const __bf16* __restrict__ Kb,
                                                 const __bf16* __restrict__ VpT,
                                                 const __bf16* __restrict__ Vb,
                                                 float* __restrict__ Out) {
  __shared__ __bf16 qs[32][260];  // 16640 B, stride 130 words == 2 mod 32
  __shared__ __bf16 ps[32][132];  // 8448 B,  stride 66 words == 2 mod 32
  const int t = threadIdx.x, lane = t & 63, w = t >> 6;
  const int ln = lane & 15, quad = lane >> 4, q8 = quad * 8;
  const int bid = blockIdx.x;      // 0..511
  const int b = bid & 3;           // batches interleave across XCDs
  const int nt = bid >> 2;         // 0..127, heavy (small nt) first
  const int n0 = nt * 32;
  const __bf16* Qp = Qb + (size_t)b * SEQ * DIM;
  const __bf16* Kp = Kb + (size_t)b * SEQ * DIM;
  const __bf16* Vt = VpT + (size_t)b * DIM * SEQ;
  // stage Q tile (32 rows x 256) once
  {
    int row = t >> 4, part = t & 15;
    const __bf16* src = &Qp[(size_t)(n0 + row) * DIM + part * 16];
    *(bf16x8*)&qs[row][part * 16] = *(const bf16x8*)&src[0];
    *(bf16x8*)&qs[row][part * 16 + 8] = *(const bf16x8*)&src[8];
  }
  __syncthreads();
  f32x4 accO[2][2] = {};  // [tn][td]
  for (int ms = (nt >> 2); ms < 32; ++ms) {
    // ---- S phase: this wave's 16 m-cols, B-frags straight from global K
    f32x4 accS[2] = {};
    const __bf16* Krow = Kp + (size_t)(ms * 128 + w * 16 + ln) * DIM;
#pragma unroll
    for (int kf = 0; kf < 8; ++kf) {
      bf16x8 bb = *(const bf16x8*)&Krow[kf * 32 + q8];
      bf16x8 a0 = *(bf16x8*)&qs[ln][kf * 32 + q8];
      bf16x8 a1 = *(bf16x8*)&qs[16 + ln][kf * 32 + q8];
      accS[0] = MFMA16(a0, bb, accS[0]);
      accS[1] = MFMA16(a1, bb, accS[1]);
    }
    __syncthreads();  // previous step's ps readers done
#pragma unroll
    for (int tn = 0; tn < 2; ++tn)
#pragma unroll
      for (int r = 0; r < 4; ++r) {
        int nl = tn * 16 + quad * 4 + r;
        int m_g = ms * 128 + w * 16 + ln;
        float e = (n0 + nl >= m_g) ? 0.f : __expf(accS[tn][r] * 0.0625f);
        ps[nl][w * 16 + ln] = (__bf16)e;
      }
    __syncthreads();
    // ---- PV phase: this wave's 32 d-cols, B-frags straight from global VpT
    const __bf16* Vr0 = Vt + (size_t)(w * 32 + ln) * SEQ + ms * 128;
    const __bf16* Vr1 = Vt + (size_t)(w * 32 + 16 + ln) * SEQ + ms * 128;
#pragma unroll
    for (int kf = 0; kf < 4; ++kf) {
      bf16x8 b0 = *(const bf16x8*)&Vr0[kf * 32 + q8];
      bf16x8 b1 = *(const bf16x8*)&Vr1[kf * 32 + q8];
      bf16x8 a0 = *(bf16x8*)&ps[ln][kf * 32 + q8];
      bf16x8 a1 = *(bf16x8*)&ps[16 + ln][kf * 32 + q8];
      accO[0][0] = MFMA16(a0, b0, accO[0][0]);
      accO[0][1] = MFMA16(a0, b1, accO[0][1]);
      accO[1][0] = MFMA16(a1, b0, accO[1][0]);
      accO[1][1] = MFMA16(a1, b1, accO[1][1]);
    }
  }
  // epilogue: + V[b,0,:]/4096 (the all-masked m=0 column), write fp32
  const __bf16* V0 = Vb + (size_t)b * SEQ * DIM;
  float* Op = Out + (size_t)b * SEQ * DIM;
#pragma unroll
  for (int tn = 0; tn < 2; ++tn)
#pragma unroll
    for (int td = 0; td < 2; ++td) {
      int col = w * 32 + td * 16 + ln;
      float c0 = (float)V0[col] * (1.0f / 4096.0f);
#pragma unroll
      for (int r = 0; r < 4; ++r) {
        int row = n0 + tn * 16 + quad * 4 + r;
        Op[(size_t)row * DIM + col] = accO[tn][td][r] + c0;
      }
    }
}

// ---------------------------------------------------------------- launch
extern "C" void kernel_launch(void* const* d_in, const int* in_sizes, int n_in,
                              void* d_out, int out_size, void* d_ws, size_t ws_size,
                              hipStream_t stream) {
  const float* x = (const float*)d_in[0];
  const float* Wq = (const float*)d_in[1];
  const float* Wk = (const float*)d_in[2];
  const float* Wv = (const float*)d_in[3];
  float* out = (float*)d_out;
  char* ws = (char*)d_ws;
  __bf16* Qb = (__bf16*)(ws);                       // 8 MB
  __bf16* Kb = (__bf16*)(ws + (8u << 20));          // 8 MB
  __bf16* Vb = (__bf16*)(ws + (16u << 20));         // 8 MB
  __bf16* VpT = (__bf16*)(ws + (24u << 20));        // 8 MB
  float* colsum = (float*)(ws + (32u << 20));       // 64 KB
  __bf16* Wb = (__bf16*)(ws + (32u << 20) + (1u << 16));  // 384 KB

  k_prep<<<dim3(768), dim3(256), 0, stream>>>(Wq, Wk, Wv, Wb, colsum);
  k_qkv<<<dim3(128, 4, 3), dim3(256), 0, stream>>>(x, Wb, Qb, Kb, Vb);
  k_colsum<<<dim3(32, 8, 4), dim3(256), 0, stream>>>(Qb, Kb, colsum);
  k_vpt<<<dim3(64, 4, 4), dim3(256), 0, stream>>>(Vb, colsum, VpT);
  k_attn<<<dim3(512), dim3(512), 0, stream>>>(Qb, Kb, VpT, Vb, out);
}

// Round 3
// 258.161 us; speedup vs baseline: 1.4366x; 1.4366x over previous
//
#include <hip/hip_runtime.h>
#include <hip/hip_bf16.h>

// MaskedAttentionLayer: B=4, N=4096, D=256, fp32 in/out.
// mask keeps strictly-future (m>n); softmax over QUERY axis (per-column).
// O = E @ (V/colsum), E = exp(S/16); col m=0 fully masked -> V[b,0,:]/4096.

typedef float f32x4 __attribute__((ext_vector_type(4)));
typedef __bf16 bf16x8 __attribute__((ext_vector_type(8)));
typedef __bf16 bf16x4 __attribute__((ext_vector_type(4)));

#define MFMA16(a, b, c) __builtin_amdgcn_mfma_f32_16x16x32_bf16((a), (b), (c), 0, 0, 0)

constexpr int SEQ = 4096;
constexpr int DIM = 256;

// ---------------------------------------------------------------- k_prep
__global__ void k_prep(const float* __restrict__ Wq, const float* __restrict__ Wk,
                       const float* __restrict__ Wv, __bf16* __restrict__ Wb,
                       float* __restrict__ colsum) {
  int i = blockIdx.x * 256 + threadIdx.x;
  if (i < 3 * 65536) {
    const float* src = (i < 65536) ? Wq : (i < 131072 ? Wk : Wv);
    Wb[i] = (__bf16)src[i & 65535];
  }
  if (i < 4 * SEQ) colsum[i] = 0.f;
}

// ---------------------------------------------------------------- k_qkv v3
// Out[z][i,j] = sum_d x[i,d] * W[z][j,d]. Grid 256 (i-tiles of 64), 256 thr.
// x rows held in registers (read once); W tiles staged contiguously in LDS.
__global__ __launch_bounds__(256, 2) void k_qkv(const float* __restrict__ x,
                                                const __bf16* __restrict__ Wb,
                                                __bf16* __restrict__ Qb,
                                                __bf16* __restrict__ Kb,
                                                __bf16* __restrict__ Vb) {
  __shared__ __bf16 wsh[64][264];
  const int t = threadIdx.x, lane = t & 63, w = t >> 6;
  const int ln = lane & 15, quad = lane >> 4, q8 = quad * 8;
  const int i0 = blockIdx.x * 64;
  // x fragments: wave owns rows [i0 + w*16, +16)
  bf16x8 xa[8];
#pragma unroll
  for (int kf = 0; kf < 8; ++kf) {
    const float* src = &x[(size_t)(i0 + w * 16 + ln) * DIM + kf * 32 + q8];
    float4 v0 = *(const float4*)&src[0];
    float4 v1 = *(const float4*)&src[4];
    xa[kf] = bf16x8{(__bf16)v0.x, (__bf16)v0.y, (__bf16)v0.z, (__bf16)v0.w,
                    (__bf16)v1.x, (__bf16)v1.y, (__bf16)v1.z, (__bf16)v1.w};
  }
  for (int zj = 0; zj < 12; ++zj) {
    const int z = zj >> 2, j0 = (zj & 3) * 64;
    const __bf16* W = Wb + z * 65536 + j0 * 256;
    bf16x8 stg[8];
#pragma unroll
    for (int i = 0; i < 8; ++i) stg[i] = *(const bf16x8*)&W[(t + i * 256) * 8];
    __syncthreads();  // previous MFMA reads of wsh done
#pragma unroll
    for (int i = 0; i < 8; ++i)
      *(bf16x8*)&wsh[(t >> 5) + i * 8][(t & 31) * 8] = stg[i];
    __syncthreads();
    f32x4 acc[4] = {};
#pragma unroll
    for (int kf = 0; kf < 8; ++kf) {
      bf16x8 bb[4];
#pragma unroll
      for (int tj = 0; tj < 4; ++tj)
        bb[tj] = *(bf16x8*)&wsh[tj * 16 + ln][kf * 32 + q8];
#pragma unroll
      for (int tj = 0; tj < 4; ++tj) acc[tj] = MFMA16(xa[kf], bb[tj], acc[tj]);
    }
    __bf16* Out = (z == 0) ? Qb : (z == 1 ? Kb : Vb);
#pragma unroll
    for (int tj = 0; tj < 4; ++tj)
#pragma unroll
      for (int r = 0; r < 4; ++r) {
        int row = i0 + w * 16 + quad * 4 + r;
        int col = j0 + tj * 16 + ln;
        Out[(size_t)row * DIM + col] = (__bf16)acc[tj][r];
      }
  }
}

// ---------------------------------------------------------------- k_colsum v3
// colsum[b,m] = sum_{n<m} exp(q_n.k_m/16). Grid (32 mt, 4 split, 4 b), 256 thr.
// K fragments (wave's 32 m-cols) in registers; Q chunks staged contiguously.
__global__ __launch_bounds__(256, 2) void k_colsum(const __bf16* __restrict__ Qb,
                                                   const __bf16* __restrict__ Kb,
                                                   float* __restrict__ colsum) {
  __shared__ __bf16 qs[64][264];
  const int t = threadIdx.x, lane = t & 63, w = t >> 6;
  const int ln = lane & 15, quad = lane >> 4, q8 = quad * 8;
  const int mt = blockIdx.x, s = blockIdx.y, b = blockIdx.z;
  const int m0 = mt * 128;
  const __bf16* Qp = Qb + (size_t)b * SEQ * DIM;
  const __bf16* Kp = Kb + (size_t)b * SEQ * DIM;
  // K fragments: wave owns m-cols [m0 + w*32, +32)
  bf16x8 kb[2][8];
#pragma unroll
  for (int tm = 0; tm < 2; ++tm)
#pragma unroll
    for (int kf = 0; kf < 8; ++kf)
      kb[tm][kf] = *(const bf16x8*)&Kp[(size_t)(m0 + w * 32 + tm * 16 + ln) * DIM + kf * 32 + q8];
  float csum[2] = {0.f, 0.f};
  for (int nc = s; nc < 2 * mt + 2; nc += 4) {
    bf16x8 stg[8];
    const __bf16* src = Qp + (size_t)nc * 64 * DIM;
#pragma unroll
    for (int i = 0; i < 8; ++i) stg[i] = *(const bf16x8*)&src[(t + i * 256) * 8];
    __syncthreads();
#pragma unroll
    for (int i = 0; i < 8; ++i)
      *(bf16x8*)&qs[(t >> 5) + i * 8][(t & 31) * 8] = stg[i];
    __syncthreads();
    f32x4 acc[4][2] = {};
#pragma unroll
    for (int kf = 0; kf < 8; ++kf) {
      bf16x8 aa[4];
#pragma unroll
      for (int tn = 0; tn < 4; ++tn) aa[tn] = *(bf16x8*)&qs[tn * 16 + ln][kf * 32 + q8];
#pragma unroll
      for (int tn = 0; tn < 4; ++tn)
#pragma unroll
        for (int tm = 0; tm < 2; ++tm)
          acc[tn][tm] = MFMA16(aa[tn], kb[tm][kf], acc[tn][tm]);
    }
#pragma unroll
    for (int tn = 0; tn < 4; ++tn)
#pragma unroll
      for (int tm = 0; tm < 2; ++tm)
#pragma unroll
        for (int r = 0; r < 4; ++r) {
          int n_g = nc * 64 + tn * 16 + quad * 4 + r;
          int m_g = m0 + w * 32 + tm * 16 + ln;
          if (n_g < m_g) csum[tm] += __expf(acc[tn][tm][r] * 0.0625f);
        }
  }
#pragma unroll
  for (int tm = 0; tm < 2; ++tm) {
    float v = csum[tm];
    v += __shfl_xor(v, 16);
    v += __shfl_xor(v, 32);
    if (quad == 0)
      atomicAdd(&colsum[b * SEQ + m0 + w * 32 + tm * 16 + ln], v);
  }
}

// ---------------------------------------------------------------- k_vpt
// Blocked transpose: VpTblk[b][mblk][d][mloc] = V[b][mblk*64+mloc][d]/colsum.
// Makes k_attn's V staging a contiguous 32 KB read per m-step.
__global__ void k_vpt(const __bf16* __restrict__ Vb, const float* __restrict__ colsum,
                      __bf16* __restrict__ VpT) {
  __shared__ __bf16 tile[64][72];
  const int t = threadIdx.x;
  const int b = blockIdx.z;
  const int m0 = blockIdx.x * 64, d0 = blockIdx.y * 64;
  {
    int row = t >> 2, part = t & 3;  // row = m-local
    float cs = colsum[b * SEQ + m0 + row];
    float inv = (m0 + row == 0) ? (1.0f / 4096.0f) : (1.0f / cs);
#pragma unroll
    for (int i = 0; i < 2; ++i) {
      int c = part * 2 + i;
      bf16x8 v = *(const bf16x8*)&Vb[(size_t)(b * SEQ + m0 + row) * DIM + d0 + c * 8];
      bf16x8 o;
#pragma unroll
      for (int j = 0; j < 8; ++j) o[j] = (__bf16)((float)v[j] * inv);
      *(bf16x8*)&tile[row][c * 8] = o;
    }
  }
  __syncthreads();
  {
    int row = t >> 2, part = t & 3;  // row = d-local
#pragma unroll
    for (int i = 0; i < 2; ++i) {
      int c = part * 2 + i;          // m chunk
      bf16x8 o;
#pragma unroll
      for (int j = 0; j < 8; ++j) o[j] = tile[c * 8 + j][row];
      *(bf16x8*)&VpT[(size_t)((b * 64 + blockIdx.x) * 256 + d0 + row) * 64 + c * 8] = o;
    }
  }
}

// ---------------------------------------------------------------- k_attn v3
// Grid (32 nt, nsplit, 4 b), 512 thr (8 waves). n-tile 128, m-step 64.
// Q (64 rows/wave) in regs; ksh/vs double-buffered; 2 barriers/step.
// S: waves = 2 n-groups x 4 m-groups (wave 64n x 16m).
// PV: waves = 2 n-groups x 4 d-groups (wave 64n x 64d).
__global__ __launch_bounds__(512, 2) void k_attn(const __bf16* __restrict__ Qb,
                                                 const __bf16* __restrict__ Kb,
                                                 const __bf16* __restrict__ Vt_blk,
                                                 const __bf16* __restrict__ Vb,
                                                 __bf16* __restrict__ opart,
                                                 float* __restrict__ out_f32,
                                                 int nsplit, int fuse) {
  __shared__ __bf16 ksh[2][64][264];  // 67584 B
  __shared__ __bf16 vs[2][256][72];   // 73728 B
  __shared__ __bf16 ps[128][72];      // 18432 B  (total 159744)
  const int t = threadIdx.x, lane = t & 63, w = t >> 6;
  const int ln = lane & 15, quad = lane >> 4, q8 = quad * 8;
  const int nt = blockIdx.x, s = blockIdx.y, b = blockIdx.z;
  const int n0 = nt * 128;
  const int wn = w & 1;   // n-group (64 rows) for both phases
  const int wm = w >> 1;  // S: m-group (16 cols); PV: d-group (64 cols)
  const __bf16* Qp = Qb + (size_t)b * SEQ * DIM;
  const __bf16* Kp = Kb + (size_t)b * SEQ * DIM;
  const __bf16* Vt = Vt_blk + (size_t)b * SEQ * DIM;  // blocked [64][256][64]
  // Q fragments: rows [n0 + wn*64, +64), all k. 128 VGPRs.
  bf16x8 qf[4][8];
#pragma unroll
  for (int tn = 0; tn < 4; ++tn)
#pragma unroll
    for (int kf = 0; kf < 8; ++kf)
      qf[tn][kf] = *(const bf16x8*)&Qp[(size_t)(n0 + wn * 64 + tn * 16 + ln) * DIM + kf * 32 + q8];
  f32x4 accO[4][4] = {};
  int ms = 2 * nt + s;
  // prologue: stage step-0 tiles into buffer 0
  if (ms < 64) {
    bf16x8 sk[4], sv[4];
    const __bf16* kp = Kp + (size_t)ms * 16384;
    const __bf16* vp = Vt + (size_t)ms * 16384;
#pragma unroll
    for (int i = 0; i < 4; ++i) sk[i] = *(const bf16x8*)&kp[(t + i * 512) * 8];
#pragma unroll
    for (int i = 0; i < 4; ++i) sv[i] = *(const bf16x8*)&vp[(t + i * 512) * 8];
#pragma unroll
    for (int i = 0; i < 4; ++i)
      *(bf16x8*)&ksh[0][(t >> 5) + i * 16][(t & 31) * 8] = sk[i];
#pragma unroll
    for (int i = 0; i < 4; ++i)
      *(bf16x8*)&vs[0][(t >> 3) + i * 64][(t & 7) * 8] = sv[i];
  }
  __syncthreads();
  for (int it = 0; ms < 64; ms += nsplit, ++it) {
    const int cur = it & 1, nxt = cur ^ 1;
    const int msn = ms + nsplit;
    // issue next-step staging loads (land during S phase)
    bf16x8 sk[4], sv[4];
    if (msn < 64) {
      const __bf16* kp = Kp + (size_t)msn * 16384;
      const __bf16* vp = Vt + (size_t)msn * 16384;
#pragma unroll
      for (int i = 0; i < 4; ++i) sk[i] = *(const bf16x8*)&kp[(t + i * 512) * 8];
#pragma unroll
      for (int i = 0; i < 4; ++i) sv[i] = *(const bf16x8*)&vp[(t + i * 512) * 8];
    }
    // ---- S phase: wave computes 64n x 16m
    f32x4 accS[4] = {};
#pragma unroll
    for (int kf = 0; kf < 8; ++kf) {
      bf16x8 bb = *(bf16x8*)&ksh[cur][wm * 16 + ln][kf * 32 + q8];
#pragma unroll
      for (int tn = 0; tn < 4; ++tn) accS[tn] = MFMA16(qf[tn][kf], bb, accS[tn]);
    }
#pragma unroll
    for (int tn = 0; tn < 4; ++tn)
#pragma unroll
      for (int r = 0; r < 4; ++r) {
        int nl = wn * 64 + tn * 16 + quad * 4 + r;
        int m_g = ms * 64 + wm * 16 + ln;
        float e = (n0 + nl >= m_g) ? 0.f : __expf(accS[tn][r] * 0.0625f);
        ps[nl][wm * 16 + ln] = (__bf16)e;
      }
    __syncthreads();  // B_mid: ps visible
    // write next-step staged tiles (consumed after B_end)
    if (msn < 64) {
#pragma unroll
      for (int i = 0; i < 4; ++i)
        *(bf16x8*)&ksh[nxt][(t >> 5) + i * 16][(t & 31) * 8] = sk[i];
#pragma unroll
      for (int i = 0; i < 4; ++i)
        *(bf16x8*)&vs[nxt][(t >> 3) + i * 64][(t & 7) * 8] = sv[i];
    }
    // ---- PV phase: wave computes 64n x 64d over K=64
#pragma unroll
    for (int kf = 0; kf < 2; ++kf) {
      bf16x8 aa[4], bb[4];
#pragma unroll
      for (int tn = 0; tn < 4; ++tn)
        aa[tn] = *(bf16x8*)&ps[wn * 64 + tn * 16 + ln][kf * 32 + q8];
#pragma unroll
      for (int td = 0; td < 4; ++td)
        bb[td] = *(bf16x8*)&vs[cur][wm * 64 + td * 16 + ln][kf * 32 + q8];
#pragma unroll
      for (int tn = 0; tn < 4; ++tn)
#pragma unroll
        for (int td = 0; td < 4; ++td)
          accO[tn][td] = MFMA16(aa[tn], bb[td], accO[tn][td]);
    }
    __syncthreads();  // B_end
  }
  // ---- epilogue
  if (fuse) {  // nsplit==1: write fp32 Out directly, add V0 term
    const __bf16* V0 = Vb + (size_t)b * SEQ * DIM;
    float* Op = out_f32 + (size_t)b * SEQ * DIM;
#pragma unroll
    for (int tn = 0; tn < 4; ++tn)
#pragma unroll
      for (int td = 0; td < 4; ++td) {
        int col = wm * 64 + td * 16 + ln;
        float c0 = (float)V0[col] * (1.0f / 4096.0f);
#pragma unroll
        for (int r = 0; r < 4; ++r) {
          int row = n0 + wn * 64 + tn * 16 + quad * 4 + r;
          Op[(size_t)row * DIM + col] = accO[tn][td][r] + c0;
        }
      }
  } else {  // bf16 partial per split
    __bf16* P = opart + (size_t)s * (4u << 20) + ((size_t)b << 20);
#pragma unroll
    for (int tn = 0; tn < 4; ++tn)
#pragma unroll
      for (int td = 0; td < 4; ++td) {
        int col = wm * 64 + td * 16 + ln;
#pragma unroll
        for (int r = 0; r < 4; ++r) {
          int row = n0 + wn * 64 + tn * 16 + quad * 4 + r;
          P[(size_t)row * DIM + col] = (__bf16)accO[tn][td][r];
        }
      }
  }
}

// ---------------------------------------------------------------- k_final
// Out = sum_s bf16(Opart[s]) + V[b,0,:]/4096. 2048 blocks x 256, 8 f32/thread.
__global__ void k_final(const __bf16* __restrict__ opart, const __bf16* __restrict__ Vb,
                        float* __restrict__ out, int nsplit) {
  const size_t base = ((size_t)blockIdx.x * 256 + threadIdx.x) * 8;
  const int b = (int)(base >> 20);
  const int d0 = (int)(base & 255);
  float sum[8] = {};
  for (int s = 0; s < nsplit; ++s) {
    bf16x8 v = *(const bf16x8*)&opart[(size_t)s * (4u << 20) + base];
#pragma unroll
    for (int j = 0; j < 8; ++j) sum[j] += (float)v[j];
  }
  bf16x8 v0 = *(const bf16x8*)&Vb[((size_t)b << 20) + d0];
  float4 o0, o1;
  o0.x = sum[0] + (float)v0[0] * (1.0f / 4096.0f);
  o0.y = sum[1] + (float)v0[1] * (1.0f / 4096.0f);
  o0.z = sum[2] + (float)v0[2] * (1.0f / 4096.0f);
  o0.w = sum[3] + (float)v0[3] * (1.0f / 4096.0f);
  o1.x = sum[4] + (float)v0[4] * (1.0f / 4096.0f);
  o1.y = sum[5] + (float)v0[5] * (1.0f / 4096.0f);
  o1.z = sum[6] + (float)v0[6] * (1.0f / 4096.0f);
  o1.w = sum[7] + (float)v0[7] * (1.0f / 4096.0f);
  *(float4*)&out[base] = o0;
  *(float4*)&out[base + 4] = o1;
}

// ---------------------------------------------------------------- launch
extern "C" void kernel_launch(void* const* d_in, const int* in_sizes, int n_in,
                              void* d_out, int out_size, void* d_ws, size_t ws_size,
                              hipStream_t stream) {
  const float* x = (const float*)d_in[0];
  const float* Wq = (const float*)d_in[1];
  const float* Wk = (const float*)d_in[2];
  const float* Wv = (const float*)d_in[3];
  float* out = (float*)d_out;
  char* ws = (char*)d_ws;
  __bf16* Qb = (__bf16*)(ws);                             // 8 MB
  __bf16* Kb = (__bf16*)(ws + (8u << 20));                // 8 MB
  __bf16* Vb = (__bf16*)(ws + (16u << 20));               // 8 MB
  __bf16* VpT = (__bf16*)(ws + (24u << 20));              // 8 MB (blocked)
  float* colsum = (float*)(ws + (32u << 20));             // 64 KB
  __bf16* Wb = (__bf16*)(ws + (32u << 20) + (1u << 16));  // 384 KB
  const size_t base = (32u << 20) + (1u << 16) + (384u << 10);
  __bf16* opart = (__bf16*)(ws + base);                   // 8 MB per split
  // choose split count from ws_size (constant per session -> capture-safe)
  int nsplit = 1;
  if (ws_size >= base + 4u * (8u << 20)) nsplit = 4;
  else if (ws_size >= base + 2u * (8u << 20)) nsplit = 2;
  const int fuse = (nsplit == 1);

  k_prep<<<dim3(768), dim3(256), 0, stream>>>(Wq, Wk, Wv, Wb, colsum);
  k_qkv<<<dim3(256), dim3(256), 0, stream>>>(x, Wb, Qb, Kb, Vb);
  k_colsum<<<dim3(32, 4, 4), dim3(256), 0, stream>>>(Qb, Kb, colsum);
  k_vpt<<<dim3(64, 4, 4), dim3(256), 0, stream>>>(Vb, colsum, VpT);
  k_attn<<<dim3(32, nsplit, 4), dim3(512), 0, stream>>>(Qb, Kb, VpT, Vb, opart, out,
                                                        nsplit, fuse);
  if (!fuse)
    k_final<<<dim3(2048), dim3(256), 0, stream>>>(opart, Vb, out, nsplit);
}

// Round 5
// 237.131 us; speedup vs baseline: 1.5640x; 1.0887x over previous
//
#include <hip/hip_runtime.h>
#include <hip/hip_bf16.h>

// MaskedAttentionLayer: B=4, N=4096, D=256, fp32 in/out.
// mask keeps strictly-future (m>n); softmax over QUERY axis (per-column).
// O = E @ (V/colsum), E = exp(S/16); col m=0 fully masked -> V[b,0,:]/4096.

typedef float f32x4 __attribute__((ext_vector_type(4)));
typedef __bf16 bf16x8 __attribute__((ext_vector_type(8)));
typedef __bf16 bf16x4 __attribute__((ext_vector_type(4)));

#define MFMA16(a, b, c) __builtin_amdgcn_mfma_f32_16x16x32_bf16((a), (b), (c), 0, 0, 0)

constexpr int SEQ = 4096;
constexpr int DIM = 256;

// ---------------------------------------------------------------- k_prep
__global__ void k_prep(const float* __restrict__ Wq, const float* __restrict__ Wk,
                       const float* __restrict__ Wv, __bf16* __restrict__ Wb,
                       float* __restrict__ colsum) {
  int i = blockIdx.x * 256 + threadIdx.x;
  if (i < 3 * 65536) {
    const float* src = (i < 65536) ? Wq : (i < 131072 ? Wk : Wv);
    Wb[i] = (__bf16)src[i & 65535];
  }
  if (i < 4 * SEQ) colsum[i] = 0.f;
}

// ---------------------------------------------------------------- k_qkv
// Out[z][i,j] = sum_d x[i,d] * W[z][j,d]. Grid 256 (i-tiles of 64), 256 thr.
__global__ __launch_bounds__(256, 2) void k_qkv(const float* __restrict__ x,
                                                const __bf16* __restrict__ Wb,
                                                __bf16* __restrict__ Qb,
                                                __bf16* __restrict__ Kb,
                                                __bf16* __restrict__ Vb) {
  __shared__ __bf16 wsh[64][264];
  const int t = threadIdx.x, lane = t & 63, w = t >> 6;
  const int ln = lane & 15, quad = lane >> 4, q8 = quad * 8;
  const int i0 = blockIdx.x * 64;
  bf16x8 xa[8];
#pragma unroll
  for (int kf = 0; kf < 8; ++kf) {
    const float* src = &x[(size_t)(i0 + w * 16 + ln) * DIM + kf * 32 + q8];
    float4 v0 = *(const float4*)&src[0];
    float4 v1 = *(const float4*)&src[4];
    xa[kf] = bf16x8{(__bf16)v0.x, (__bf16)v0.y, (__bf16)v0.z, (__bf16)v0.w,
                    (__bf16)v1.x, (__bf16)v1.y, (__bf16)v1.z, (__bf16)v1.w};
  }
  for (int zj = 0; zj < 12; ++zj) {
    const int z = zj >> 2, j0 = (zj & 3) * 64;
    const __bf16* W = Wb + z * 65536 + j0 * 256;
    bf16x8 stg[8];
#pragma unroll
    for (int i = 0; i < 8; ++i) stg[i] = *(const bf16x8*)&W[(t + i * 256) * 8];
    __syncthreads();
#pragma unroll
    for (int i = 0; i < 8; ++i)
      *(bf16x8*)&wsh[(t >> 5) + i * 8][(t & 31) * 8] = stg[i];
    __syncthreads();
    f32x4 acc[4] = {};
#pragma unroll
    for (int kf = 0; kf < 8; ++kf) {
      bf16x8 bb[4];
#pragma unroll
      for (int tj = 0; tj < 4; ++tj)
        bb[tj] = *(bf16x8*)&wsh[tj * 16 + ln][kf * 32 + q8];
#pragma unroll
      for (int tj = 0; tj < 4; ++tj) acc[tj] = MFMA16(xa[kf], bb[tj], acc[tj]);
    }
    __bf16* Out = (z == 0) ? Qb : (z == 1 ? Kb : Vb);
#pragma unroll
    for (int tj = 0; tj < 4; ++tj)
#pragma unroll
      for (int r = 0; r < 4; ++r) {
        int row = i0 + w * 16 + quad * 4 + r;
        int col = j0 + tj * 16 + ln;
        Out[(size_t)row * DIM + col] = (__bf16)acc[tj][r];
      }
  }
}

// ---------------------------------------------------------------- k_colsum
// colsum[b,m] = sum_{n<m} exp(q_n.k_m/16). 512 blocks x 256 thr.
// r3-verified body; new mapping: XCD-pinned batch, round-reversal balance,
// aligned ascending n-sweep (stride 4 across 4 splits).
__global__ __launch_bounds__(256, 2) void k_colsum(const __bf16* __restrict__ Qb,
                                                   const __bf16* __restrict__ Kb,
                                                   float* __restrict__ colsum) {
  __shared__ __bf16 qs[64][264];
  const int t = threadIdx.x, lane = t & 63, w = t >> 6;
  const int ln = lane & 15, quad = lane >> 4, q8 = quad * 8;
  const int bid = blockIdx.x;
  const int b = (bid & 7) >> 1;                 // XCD-pair pinned batch
  const int i = ((bid >> 3) << 1) | (bid & 1);  // 0..127
  const int round = i >> 6, k = i & 63;
  const int mt = round ? 31 - (k & 31) : (k & 31);  // reversal balances CU pairs
  const int s = (k >> 5) | (round << 1);            // split 0..3
  const int m0 = mt * 128;
  const __bf16* Qp = Qb + (size_t)b * SEQ * DIM;
  const __bf16* Kp = Kb + (size_t)b * SEQ * DIM;
  // K fragments: wave owns m-cols [m0 + w*32, +32)
  bf16x8 kb[2][8];
#pragma unroll
  for (int tm = 0; tm < 2; ++tm)
#pragma unroll
    for (int kf = 0; kf < 8; ++kf)
      kb[tm][kf] = *(const bf16x8*)&Kp[(size_t)(m0 + w * 32 + tm * 16 + ln) * DIM + kf * 32 + q8];
  float csum[2] = {0.f, 0.f};
  for (int nc = s; nc < 2 * mt + 2; nc += 4) {
    bf16x8 stg[8];
    const __bf16* src = Qp + (size_t)nc * 64 * DIM;
#pragma unroll
    for (int i2 = 0; i2 < 8; ++i2) stg[i2] = *(const bf16x8*)&src[(t + i2 * 256) * 8];
    __syncthreads();
#pragma unroll
    for (int i2 = 0; i2 < 8; ++i2)
      *(bf16x8*)&qs[(t >> 5) + i2 * 8][(t & 31) * 8] = stg[i2];
    __syncthreads();
    f32x4 acc[4][2] = {};
#pragma unroll
    for (int kf = 0; kf < 8; ++kf) {
      bf16x8 aa[4];
#pragma unroll
      for (int tn = 0; tn < 4; ++tn) aa[tn] = *(bf16x8*)&qs[tn * 16 + ln][kf * 32 + q8];
#pragma unroll
      for (int tn = 0; tn < 4; ++tn)
#pragma unroll
        for (int tm = 0; tm < 2; ++tm)
          acc[tn][tm] = MFMA16(aa[tn], kb[tm][kf], acc[tn][tm]);
    }
#pragma unroll
    for (int tn = 0; tn < 4; ++tn)
#pragma unroll
      for (int tm = 0; tm < 2; ++tm)
#pragma unroll
        for (int r = 0; r < 4; ++r) {
          int n_g = nc * 64 + tn * 16 + quad * 4 + r;
          int m_g = m0 + w * 32 + tm * 16 + ln;
          if (n_g < m_g) csum[tm] += __expf(acc[tn][tm][r] * 0.0625f);
        }
  }
#pragma unroll
  for (int tm = 0; tm < 2; ++tm) {
    float v = csum[tm];
    v += __shfl_xor(v, 16);
    v += __shfl_xor(v, 32);
    if (quad == 0)
      atomicAdd(&colsum[b * SEQ + m0 + w * 32 + tm * 16 + ln], v);
  }
}

// ---------------------------------------------------------------- k_vpt
// Blocked transpose: VpTblk[b][mblk][d][mloc] = V[b][mblk*64+mloc][d]/colsum.
__global__ void k_vpt(const __bf16* __restrict__ Vb, const float* __restrict__ colsum,
                      __bf16* __restrict__ VpT) {
  __shared__ __bf16 tile[64][72];
  const int t = threadIdx.x;
  const int b = blockIdx.z;
  const int m0 = blockIdx.x * 64, d0 = blockIdx.y * 64;
  {
    int row = t >> 2, part = t & 3;
    float cs = colsum[b * SEQ + m0 + row];
    float inv = (m0 + row == 0) ? (1.0f / 4096.0f) : (1.0f / cs);
#pragma unroll
    for (int i = 0; i < 2; ++i) {
      int c = part * 2 + i;
      bf16x8 v = *(const bf16x8*)&Vb[(size_t)(b * SEQ + m0 + row) * DIM + d0 + c * 8];
      bf16x8 o;
#pragma unroll
      for (int j = 0; j < 8; ++j) o[j] = (__bf16)((float)v[j] * inv);
      *(bf16x8*)&tile[row][c * 8] = o;
    }
  }
  __syncthreads();
  {
    int row = t >> 2, part = t & 3;
#pragma unroll
    for (int i = 0; i < 2; ++i) {
      int c = part * 2 + i;
      bf16x8 o;
#pragma unroll
      for (int j = 0; j < 8; ++j) o[j] = tile[c * 8 + j][row];
      *(bf16x8*)&VpT[(size_t)((b * 64 + blockIdx.x) * 256 + d0 + row) * 64 + c * 8] = o;
    }
  }
}

// ---------------------------------------------------------------- k_attn v5
// r3-verified body (register-staged dbuf LDS, S then PV), new schedule:
// XCD-pinned batch, round-reversal balance, aligned DESCENDING m-sweep.
// Grid 128*nsplit (1D), 512 thr (8 waves). n-tile 128, m-step 64.
__global__ __launch_bounds__(512, 2) void k_attn(const __bf16* __restrict__ Qb,
                                                 const __bf16* __restrict__ Kb,
                                                 const __bf16* __restrict__ Vt_blk,
                                                 const __bf16* __restrict__ Vb,
                                                 __bf16* __restrict__ opart,
                                                 float* __restrict__ out_f32,
                                                 int nsplit, int fuse) {
  __shared__ __bf16 ksh[2][64][264];  // 67584 B
  __shared__ __bf16 vs[2][256][72];   // 73728 B
  __shared__ __bf16 ps[128][72];      // 18432 B  (total 159744)
  const int t = threadIdx.x, lane = t & 63, w = t >> 6;
  const int ln = lane & 15, quad = lane >> 4, q8 = quad * 8;
  const int wn = w & 1;   // n-group (64 rows) both phases
  const int wm = w >> 1;  // S: m-group (16 cols); PV: d-group (64 cols)
  const int bid = blockIdx.x;                   // 0..128*nsplit-1
  const int b = (bid & 7) >> 1;                 // XCD-pair pinned batch
  const int i = ((bid >> 3) << 1) | (bid & 1);  // 0..32*nsplit-1
  int nt, s;
  if (nsplit == 4) {
    int round = i >> 6, k = i & 63;
    nt = round ? 31 - (k & 31) : (k & 31);  // reversal balances CU pairs
    s = (k >> 5) | (round << 1);
  } else if (nsplit == 2) {
    s = i >> 5;
    nt = i & 31;
  } else {
    s = 0;
    nt = i & 31;
  }
  const int n0 = nt * 128;
  const __bf16* Qp = Qb + (size_t)b * SEQ * DIM;
  const __bf16* Kp = Kb + (size_t)b * SEQ * DIM;
  const __bf16* Vt = Vt_blk + (size_t)b * SEQ * DIM;  // [64][256][64] blocked
  // Q fragments: rows [n0 + wn*64, +64), all k. 128 VGPRs.
  bf16x8 qf[4][8];
#pragma unroll
  for (int tn = 0; tn < 4; ++tn)
#pragma unroll
    for (int kf = 0; kf < 8; ++kf)
      qf[tn][kf] = *(const bf16x8*)&Qp[(size_t)(n0 + wn * 64 + tn * 16 + ln) * DIM + kf * 32 + q8];
  f32x4 accO[4][4] = {};
  const int msEnd = 2 * nt;
  int ms = 63 - s;
  // prologue: stage step-0 tiles into buffer 0 (r3-verified store pattern)
  if (ms >= msEnd) {
    bf16x8 sk[4], sv[4];
    const __bf16* kp = Kp + (size_t)ms * 16384;
    const __bf16* vp = Vt + (size_t)ms * 16384;
#pragma unroll
    for (int i2 = 0; i2 < 4; ++i2) sk[i2] = *(const bf16x8*)&kp[(t + i2 * 512) * 8];
#pragma unroll
    for (int i2 = 0; i2 < 4; ++i2) sv[i2] = *(const bf16x8*)&vp[(t + i2 * 512) * 8];
#pragma unroll
    for (int i2 = 0; i2 < 4; ++i2)
      *(bf16x8*)&ksh[0][(t >> 5) + i2 * 16][(t & 31) * 8] = sk[i2];
#pragma unroll
    for (int i2 = 0; i2 < 4; ++i2)
      *(bf16x8*)&vs[0][(t >> 3) + i2 * 64][(t & 7) * 8] = sv[i2];
  }
  __syncthreads();
  for (int it = 0; ms >= msEnd; ms -= nsplit, ++it) {
    const int cur = it & 1, nxt = cur ^ 1;
    const int msn = ms - nsplit;
    // issue next-step staging loads (fly during S phase)
    bf16x8 sk[4], sv[4];
    if (msn >= msEnd) {
      const __bf16* kp = Kp + (size_t)msn * 16384;
      const __bf16* vp = Vt + (size_t)msn * 16384;
#pragma unroll
      for (int i2 = 0; i2 < 4; ++i2) sk[i2] = *(const bf16x8*)&kp[(t + i2 * 512) * 8];
#pragma unroll
      for (int i2 = 0; i2 < 4; ++i2) sv[i2] = *(const bf16x8*)&vp[(t + i2 * 512) * 8];
    }
    // ---- S phase: wave computes 64n x 16m
    f32x4 accS[4] = {};
#pragma unroll
    for (int kf = 0; kf < 8; ++kf) {
      bf16x8 bb = *(bf16x8*)&ksh[cur][wm * 16 + ln][kf * 32 + q8];
#pragma unroll
      for (int tn = 0; tn < 4; ++tn) accS[tn] = MFMA16(qf[tn][kf], bb, accS[tn]);
    }
#pragma unroll
    for (int tn = 0; tn < 4; ++tn)
#pragma unroll
      for (int r = 0; r < 4; ++r) {
        int nl = wn * 64 + tn * 16 + quad * 4 + r;
        int m_g = ms * 64 + wm * 16 + ln;
        float e = (n0 + nl >= m_g) ? 0.f : __expf(accS[tn][r] * 0.0625f);
        ps[nl][wm * 16 + ln] = (__bf16)e;
      }
    __syncthreads();  // B_mid: ps visible
    if (msn >= msEnd) {
#pragma unroll
      for (int i2 = 0; i2 < 4; ++i2)
        *(bf16x8*)&ksh[nxt][(t >> 5) + i2 * 16][(t & 31) * 8] = sk[i2];
#pragma unroll
      for (int i2 = 0; i2 < 4; ++i2)
        *(bf16x8*)&vs[nxt][(t >> 3) + i2 * 64][(t & 7) * 8] = sv[i2];
    }
    // ---- PV phase: wave computes 64n x 64d over K=64
#pragma unroll
    for (int kf = 0; kf < 2; ++kf) {
      bf16x8 aa[4], bb[4];
#pragma unroll
      for (int tn = 0; tn < 4; ++tn)
        aa[tn] = *(bf16x8*)&ps[wn * 64 + tn * 16 + ln][kf * 32 + q8];
#pragma unroll
      for (int td = 0; td < 4; ++td)
        bb[td] = *(bf16x8*)&vs[cur][wm * 64 + td * 16 + ln][kf * 32 + q8];
#pragma unroll
      for (int tn = 0; tn < 4; ++tn)
#pragma unroll
        for (int td = 0; td < 4; ++td)
          accO[tn][td] = MFMA16(aa[tn], bb[td], accO[tn][td]);
    }
    __syncthreads();  // B_end
  }
  // ---- epilogue
  if (fuse) {
    const __bf16* V0 = Vb + (size_t)b * SEQ * DIM;
    float* Op = out_f32 + (size_t)b * SEQ * DIM;
#pragma unroll
    for (int tn = 0; tn < 4; ++tn)
#pragma unroll
      for (int td = 0; td < 4; ++td) {
        int col = wm * 64 + td * 16 + ln;
        float c0 = (float)V0[col] * (1.0f / 4096.0f);
#pragma unroll
        for (int r = 0; r < 4; ++r) {
          int row = n0 + wn * 64 + tn * 16 + quad * 4 + r;
          Op[(size_t)row * DIM + col] = accO[tn][td][r] + c0;
        }
      }
  } else {
    __bf16* P = opart + (size_t)s * (4u << 20) + ((size_t)b << 20);
#pragma unroll
    for (int tn = 0; tn < 4; ++tn)
#pragma unroll
      for (int td = 0; td < 4; ++td) {
        int col = wm * 64 + td * 16 + ln;
#pragma unroll
        for (int r = 0; r < 4; ++r) {
          int row = n0 + wn * 64 + tn * 16 + quad * 4 + r;
          P[(size_t)row * DIM + col] = (__bf16)accO[tn][td][r];
        }
      }
  }
}

// ---------------------------------------------------------------- k_final
// Out = sum_s bf16(Opart[s]) + V[b,0,:]/4096. 2048 blocks x 256.
__global__ void k_final(const __bf16* __restrict__ opart, const __bf16* __restrict__ Vb,
                        float* __restrict__ out, int nsplit) {
  const size_t base = ((size_t)blockIdx.x * 256 + threadIdx.x) * 8;
  const int b = (int)(base >> 20);
  const int d0 = (int)(base & 255);
  float sum[8] = {};
  for (int s = 0; s < nsplit; ++s) {
    bf16x8 v = *(const bf16x8*)&opart[(size_t)s * (4u << 20) + base];
#pragma unroll
    for (int j = 0; j < 8; ++j) sum[j] += (float)v[j];
  }
  bf16x8 v0 = *(const bf16x8*)&Vb[((size_t)b << 20) + d0];
  float4 o0, o1;
  o0.x = sum[0] + (float)v0[0] * (1.0f / 4096.0f);
  o0.y = sum[1] + (float)v0[1] * (1.0f / 4096.0f);
  o0.z = sum[2] + (float)v0[2] * (1.0f / 4096.0f);
  o0.w = sum[3] + (float)v0[3] * (1.0f / 4096.0f);
  o1.x = sum[4] + (float)v0[4] * (1.0f / 4096.0f);
  o1.y = sum[5] + (float)v0[5] * (1.0f / 4096.0f);
  o1.z = sum[6] + (float)v0[6] * (1.0f / 4096.0f);
  o1.w = sum[7] + (float)v0[7] * (1.0f / 4096.0f);
  *(float4*)&out[base] = o0;
  *(float4*)&out[base + 4] = o1;
}

// ---------------------------------------------------------------- launch
extern "C" void kernel_launch(void* const* d_in, const int* in_sizes, int n_in,
                              void* d_out, int out_size, void* d_ws, size_t ws_size,
                              hipStream_t stream) {
  const float* x = (const float*)d_in[0];
  const float* Wq = (const float*)d_in[1];
  const float* Wk = (const float*)d_in[2];
  const float* Wv = (const float*)d_in[3];
  float* out = (float*)d_out;
  char* ws = (char*)d_ws;
  __bf16* Qb = (__bf16*)(ws);                             // 8 MB
  __bf16* Kb = (__bf16*)(ws + (8u << 20));                // 8 MB
  __bf16* Vb = (__bf16*)(ws + (16u << 20));               // 8 MB
  __bf16* VpT = (__bf16*)(ws + (24u << 20));              // 8 MB (blocked)
  float* colsum = (float*)(ws + (32u << 20));             // 64 KB
  __bf16* Wb = (__bf16*)(ws + (32u << 20) + (1u << 16));  // 384 KB
  const size_t base = (32u << 20) + (1u << 16) + (384u << 10);
  __bf16* opart = (__bf16*)(ws + base);                   // 8 MB per split
  // choose split count from ws_size (constant per session -> capture-safe)
  int nsplit = 1;
  if (ws_size >= base + 4u * (8u << 20)) nsplit = 4;
  else if (ws_size >= base + 2u * (8u << 20)) nsplit = 2;
  const int fuse = (nsplit == 1);

  k_prep<<<dim3(768), dim3(256), 0, stream>>>(Wq, Wk, Wv, Wb, colsum);
  k_qkv<<<dim3(256), dim3(256), 0, stream>>>(x, Wb, Qb, Kb, Vb);
  k_colsum<<<dim3(512), dim3(256), 0, stream>>>(Qb, Kb, colsum);
  k_vpt<<<dim3(64, 4, 4), dim3(256), 0, stream>>>(Vb, colsum, VpT);
  k_attn<<<dim3(128 * nsplit), dim3(512), 0, stream>>>(Qb, Kb, VpT, Vb, opart, out,
                                                       nsplit, fuse);
  if (!fuse)
    k_final<<<dim3(2048), dim3(256), 0, stream>>>(opart, Vb, out, nsplit);
}

// Round 6
// 208.645 us; speedup vs baseline: 1.7776x; 1.1365x over previous
//
#include <hip/hip_runtime.h>
#include <hip/hip_bf16.h>

// MaskedAttentionLayer: B=4, N=4096, D=256, fp32 in/out.
// mask keeps strictly-future (m>n); softmax over QUERY axis (per-column).
// O = E @ (V/colsum), E = exp(S/16); col m=0 fully masked -> V[b,0,:]/4096.

typedef float f32x4 __attribute__((ext_vector_type(4)));
typedef __bf16 bf16x8 __attribute__((ext_vector_type(8)));
typedef __bf16 bf16x4 __attribute__((ext_vector_type(4)));

#define MFMA16(a, b, c) __builtin_amdgcn_mfma_f32_16x16x32_bf16((a), (b), (c), 0, 0, 0)

constexpr int SEQ = 4096;
constexpr int DIM = 256;

// async global->LDS DMA, 16B/lane (dest = wave-uniform base + lane*16)
__device__ __forceinline__ void gl16(const __bf16* g, __bf16* l) {
  __builtin_amdgcn_global_load_lds((const __attribute__((address_space(1))) void*)g,
                                   (__attribute__((address_space(3))) void*)l, 16, 0, 0);
}

// ---------------------------------------------------------------- k_prep
__global__ void k_prep(const float* __restrict__ Wq, const float* __restrict__ Wk,
                       const float* __restrict__ Wv, __bf16* __restrict__ Wb,
                       float* __restrict__ colsum) {
  int i = blockIdx.x * 256 + threadIdx.x;
  if (i < 3 * 65536) {
    const float* src = (i < 65536) ? Wq : (i < 131072 ? Wk : Wv);
    Wb[i] = (__bf16)src[i & 65535];
  }
  if (i < 4 * SEQ) colsum[i] = 0.f;
}

// ---------------------------------------------------------------- k_qkv
__global__ __launch_bounds__(256, 2) void k_qkv(const float* __restrict__ x,
                                                const __bf16* __restrict__ Wb,
                                                __bf16* __restrict__ Qb,
                                                __bf16* __restrict__ Kb,
                                                __bf16* __restrict__ Vb) {
  __shared__ __bf16 wsh[64][264];
  const int t = threadIdx.x, lane = t & 63, w = t >> 6;
  const int ln = lane & 15, quad = lane >> 4, q8 = quad * 8;
  const int i0 = blockIdx.x * 64;
  bf16x8 xa[8];
#pragma unroll
  for (int kf = 0; kf < 8; ++kf) {
    const float* src = &x[(size_t)(i0 + w * 16 + ln) * DIM + kf * 32 + q8];
    float4 v0 = *(const float4*)&src[0];
    float4 v1 = *(const float4*)&src[4];
    xa[kf] = bf16x8{(__bf16)v0.x, (__bf16)v0.y, (__bf16)v0.z, (__bf16)v0.w,
                    (__bf16)v1.x, (__bf16)v1.y, (__bf16)v1.z, (__bf16)v1.w};
  }
  for (int zj = 0; zj < 12; ++zj) {
    const int z = zj >> 2, j0 = (zj & 3) * 64;
    const __bf16* W = Wb + z * 65536 + j0 * 256;
    bf16x8 stg[8];
#pragma unroll
    for (int i = 0; i < 8; ++i) stg[i] = *(const bf16x8*)&W[(t + i * 256) * 8];
    __syncthreads();
#pragma unroll
    for (int i = 0; i < 8; ++i)
      *(bf16x8*)&wsh[(t >> 5) + i * 8][(t & 31) * 8] = stg[i];
    __syncthreads();
    f32x4 acc[4] = {};
#pragma unroll
    for (int kf = 0; kf < 8; ++kf) {
      bf16x8 bb[4];
#pragma unroll
      for (int tj = 0; tj < 4; ++tj)
        bb[tj] = *(bf16x8*)&wsh[tj * 16 + ln][kf * 32 + q8];
#pragma unroll
      for (int tj = 0; tj < 4; ++tj) acc[tj] = MFMA16(xa[kf], bb[tj], acc[tj]);
    }
    __bf16* Out = (z == 0) ? Qb : (z == 1 ? Kb : Vb);
#pragma unroll
    for (int tj = 0; tj < 4; ++tj)
#pragma unroll
      for (int r = 0; r < 4; ++r) {
        int row = i0 + w * 16 + quad * 4 + r;
        int col = j0 + tj * 16 + ln;
        Out[(size_t)row * DIM + col] = (__bf16)acc[tj][r];
      }
  }
}

// ---------------------------------------------------------------- k_colsum
// (r5-verified, unchanged)
__global__ __launch_bounds__(256, 2) void k_colsum(const __bf16* __restrict__ Qb,
                                                   const __bf16* __restrict__ Kb,
                                                   float* __restrict__ colsum) {
  __shared__ __bf16 qs[64][264];
  const int t = threadIdx.x, lane = t & 63, w = t >> 6;
  const int ln = lane & 15, quad = lane >> 4, q8 = quad * 8;
  const int bid = blockIdx.x;
  const int b = (bid & 7) >> 1;
  const int i = ((bid >> 3) << 1) | (bid & 1);
  const int round = i >> 6, k = i & 63;
  const int mt = round ? 31 - (k & 31) : (k & 31);
  const int s = (k >> 5) | (round << 1);
  const int m0 = mt * 128;
  const __bf16* Qp = Qb + (size_t)b * SEQ * DIM;
  const __bf16* Kp = Kb + (size_t)b * SEQ * DIM;
  bf16x8 kb[2][8];
#pragma unroll
  for (int tm = 0; tm < 2; ++tm)
#pragma unroll
    for (int kf = 0; kf < 8; ++kf)
      kb[tm][kf] = *(const bf16x8*)&Kp[(size_t)(m0 + w * 32 + tm * 16 + ln) * DIM + kf * 32 + q8];
  float csum[2] = {0.f, 0.f};
  for (int nc = s; nc < 2 * mt + 2; nc += 4) {
    bf16x8 stg[8];
    const __bf16* src = Qp + (size_t)nc * 64 * DIM;
#pragma unroll
    for (int i2 = 0; i2 < 8; ++i2) stg[i2] = *(const bf16x8*)&src[(t + i2 * 256) * 8];
    __syncthreads();
#pragma unroll
    for (int i2 = 0; i2 < 8; ++i2)
      *(bf16x8*)&qs[(t >> 5) + i2 * 8][(t & 31) * 8] = stg[i2];
    __syncthreads();
    f32x4 acc[4][2] = {};
#pragma unroll
    for (int kf = 0; kf < 8; ++kf) {
      bf16x8 aa[4];
#pragma unroll
      for (int tn = 0; tn < 4; ++tn) aa[tn] = *(bf16x8*)&qs[tn * 16 + ln][kf * 32 + q8];
#pragma unroll
      for (int tn = 0; tn < 4; ++tn)
#pragma unroll
        for (int tm = 0; tm < 2; ++tm)
          acc[tn][tm] = MFMA16(aa[tn], kb[tm][kf], acc[tn][tm]);
    }
#pragma unroll
    for (int tn = 0; tn < 4; ++tn)
#pragma unroll
      for (int tm = 0; tm < 2; ++tm)
#pragma unroll
        for (int r = 0; r < 4; ++r) {
          int n_g = nc * 64 + tn * 16 + quad * 4 + r;
          int m_g = m0 + w * 32 + tm * 16 + ln;
          if (n_g < m_g) csum[tm] += __expf(acc[tn][tm][r] * 0.0625f);
        }
  }
#pragma unroll
  for (int tm = 0; tm < 2; ++tm) {
    float v = csum[tm];
    v += __shfl_xor(v, 16);
    v += __shfl_xor(v, 32);
    if (quad == 0)
      atomicAdd(&colsum[b * SEQ + m0 + w * 32 + tm * 16 + ln], v);
  }
}

// ---------------------------------------------------------------- k_vpt
// (r5-verified, unchanged) VpTblk[b][mblk64][d][mloc] = V/colsum.
__global__ void k_vpt(const __bf16* __restrict__ Vb, const float* __restrict__ colsum,
                      __bf16* __restrict__ VpT) {
  __shared__ __bf16 tile[64][72];
  const int t = threadIdx.x;
  const int b = blockIdx.z;
  const int m0 = blockIdx.x * 64, d0 = blockIdx.y * 64;
  {
    int row = t >> 2, part = t & 3;
    float cs = colsum[b * SEQ + m0 + row];
    float inv = (m0 + row == 0) ? (1.0f / 4096.0f) : (1.0f / cs);
#pragma unroll
    for (int i = 0; i < 2; ++i) {
      int c = part * 2 + i;
      bf16x8 v = *(const bf16x8*)&Vb[(size_t)(b * SEQ + m0 + row) * DIM + d0 + c * 8];
      bf16x8 o;
#pragma unroll
      for (int j = 0; j < 8; ++j) o[j] = (__bf16)((float)v[j] * inv);
      *(bf16x8*)&tile[row][c * 8] = o;
    }
  }
  __syncthreads();
  {
    int row = t >> 2, part = t & 3;
#pragma unroll
    for (int i = 0; i < 2; ++i) {
      int c = part * 2 + i;
      bf16x8 o;
#pragma unroll
      for (int j = 0; j < 8; ++j) o[j] = tile[c * 8 + j][row];
      *(bf16x8*)&VpT[(size_t)((b * 64 + blockIdx.x) * 256 + d0 + row) * 64 + c * 8] = o;
    }
  }
}

// ---------------------------------------------------------------- k_attn v7
// 256*nsplit blocks x 256 thr (4 waves). n-tile 64, m-step 64.
// 2 blocks/CU: LDS 74.75 KB (pad-free swizzled ksh/vs via global_load_lds,
// zero staging VGPRs; padded ps separate). 4 barriers/step; K gl16 flies
// over exp+PV, V gl16 over B3; co-resident block hides drains.
__global__ __launch_bounds__(256, 2) void k_attn(const __bf16* __restrict__ Qb,
                                                 const __bf16* __restrict__ Kb,
                                                 const __bf16* __restrict__ Vt_blk,
                                                 const __bf16* __restrict__ Vb,
                                                 __bf16* __restrict__ opart,
                                                 float* __restrict__ out_f32,
                                                 int nsplit, int fuse) {
  __shared__ __bf16 ksh[64 * 256];  // 32768 B, XOR-swizzled groups
  __shared__ __bf16 vsm[256 * 64];  // 32768 B, XOR-swizzled groups
  __shared__ __bf16 ps[64 * 72];    //  9216 B (pad 8)
  const int t = threadIdx.x, lane = t & 63, w = t >> 6;
  const int ln = lane & 15, quad = lane >> 4, q8 = quad * 8;
  const int wn = w & 1;   // n-half (32 rows) both phases
  const int wm = w >> 1;  // S: m-half (32 cols); PV: d-half (128 cols)
  const int bid = blockIdx.x;
  const int b = (bid & 7) >> 1;                 // XCD-pair pinned batch
  const int i = ((bid >> 3) << 1) | (bid & 1);  // 0..32*nsplit-1
  int nt, s;
  if (nsplit == 1) {
    nt = i & 63; s = 0;
  } else {  // nsplit 2 or 4: rounds of 64, odd rounds reversed
    int round = i >> 6, k = i & 63;
    nt = (round & 1) ? 63 - k : k;
    s = round;
  }
  const int n0 = nt * 64;
  const __bf16* Qp = Qb + (size_t)b * SEQ * DIM;
  const __bf16* Kp = Kb + (size_t)b * SEQ * DIM;
  const __bf16* Vt = Vt_blk + (size_t)b * SEQ * DIM;  // [64][256][64] blocked
  // Q fragments: rows [n0 + wn*32, +32): 64 VGPRs.
  bf16x8 qf[2][8];
#pragma unroll
  for (int tn = 0; tn < 2; ++tn)
#pragma unroll
    for (int kf = 0; kf < 8; ++kf)
      qf[tn][kf] = *(const bf16x8*)&Qp[(size_t)(n0 + wn * 32 + tn * 16 + ln) * DIM + kf * 32 + q8];
  // swizzled async staging: K tile 64x256, V tile 256x64 (2048 16B slots each)
  auto stageK = [&](int msv) {
    const __bf16* kp = Kp + (size_t)msv * 16384;
#pragma unroll
    for (int i2 = 0; i2 < 8; ++i2) {
      int sl = t + i2 * 256;
      int row = sl >> 5, g = sl & 31;
      gl16(&kp[row * 256 + ((g ^ (row & 15)) << 3)], &ksh[sl * 8]);
    }
  };
  auto stageV = [&](int msv) {
    const __bf16* vp = Vt + (size_t)msv * 16384;
#pragma unroll
    for (int i2 = 0; i2 < 8; ++i2) {
      int sl = t + i2 * 256;
      int d = sl >> 3, g = sl & 7;
      gl16(&vp[d * 64 + ((g ^ (d & 7)) << 3)], &vsm[sl * 8]);
    }
  };
  f32x4 accO[2][8] = {};  // [tn][td]
  const int msEnd = nt;
  int ms = 63 - s;
  if (ms >= msEnd) { stageK(ms); stageV(ms); }
  __syncthreads();
  for (; ms >= msEnd; ms -= nsplit) {
    const int msn = ms - nsplit;
    // ---- S phase: wave computes 32n x 32m, K from swizzled ksh
    f32x4 accS[2][2] = {};
#pragma unroll
    for (int kf = 0; kf < 8; ++kf) {
      bf16x8 bb[2];
#pragma unroll
      for (int tm = 0; tm < 2; ++tm) {
        int row = wm * 32 + tm * 16 + ln;
        bb[tm] = *(const bf16x8*)&ksh[row * 256 + (((kf * 4 + quad) ^ ln) << 3)];
      }
#pragma unroll
      for (int tn = 0; tn < 2; ++tn)
#pragma unroll
        for (int tm = 0; tm < 2; ++tm)
          accS[tn][tm] = MFMA16(qf[tn][kf], bb[tm], accS[tn][tm]);
    }
    __syncthreads();  // B0: all ksh reads done
    if (msn >= msEnd) stageK(msn);  // flies over exp+B1+PV
    // mask + exp -> ps [64 n][72]
#pragma unroll
    for (int tn = 0; tn < 2; ++tn)
#pragma unroll
      for (int tm = 0; tm < 2; ++tm) {
        int ml = wm * 32 + tm * 16 + ln;
        int m_g = ms * 64 + ml;
#pragma unroll
        for (int r = 0; r < 4; ++r) {
          int nl = wn * 32 + tn * 16 + quad * 4 + r;
          float e = (n0 + nl >= m_g) ? 0.f : __expf(accS[tn][tm][r] * 0.0625f);
          ps[nl * 72 + ml] = (__bf16)e;
        }
      }
    __syncthreads();  // B1: ps visible (also drains stageK)
    // ---- PV: O[n][d] += P[n][m] * VpT[d][m], V from swizzled vsm
#pragma unroll
    for (int kf = 0; kf < 2; ++kf) {
      bf16x8 aa[2];
#pragma unroll
      for (int tn = 0; tn < 2; ++tn)
        aa[tn] = *(const bf16x8*)&ps[(wn * 32 + tn * 16 + ln) * 72 + kf * 32 + q8];
#pragma unroll
      for (int td = 0; td < 8; ++td) {
        int d = wm * 128 + td * 16 + ln;
        bf16x8 bb = *(const bf16x8*)&vsm[d * 64 + (((kf * 4 + quad) ^ (ln & 7)) << 3)];
#pragma unroll
        for (int tn = 0; tn < 2; ++tn) accO[tn][td] = MFMA16(aa[tn], bb, accO[tn][td]);
      }
    }
    __syncthreads();  // B2: vsm/ps reads done
    if (msn >= msEnd) stageV(msn);
    __syncthreads();  // B3: staged tiles visible (drains gl16s)
  }
  // ---- epilogue
  if (fuse) {
    const __bf16* V0 = Vb + (size_t)b * SEQ * DIM;
    float* Op = out_f32 + (size_t)b * SEQ * DIM;
#pragma unroll
    for (int tn = 0; tn < 2; ++tn)
#pragma unroll
      for (int td = 0; td < 8; ++td) {
        int col = wm * 128 + td * 16 + ln;
        float c0 = (float)V0[col] * (1.0f / 4096.0f);
#pragma unroll
        for (int r = 0; r < 4; ++r) {
          int row = n0 + wn * 32 + tn * 16 + quad * 4 + r;
          Op[(size_t)row * DIM + col] = accO[tn][td][r] + c0;
        }
      }
  } else {
    __bf16* P = opart + (size_t)s * (4u << 20) + ((size_t)b << 20);
#pragma unroll
    for (int tn = 0; tn < 2; ++tn)
#pragma unroll
      for (int td = 0; td < 8; ++td) {
        int col = wm * 128 + td * 16 + ln;
#pragma unroll
        for (int r = 0; r < 4; ++r) {
          int row = n0 + wn * 32 + tn * 16 + quad * 4 + r;
          P[(size_t)row * DIM + col] = (__bf16)accO[tn][td][r];
        }
      }
  }
}

// ---------------------------------------------------------------- k_final
__global__ void k_final(const __bf16* __restrict__ opart, const __bf16* __restrict__ Vb,
                        float* __restrict__ out, int nsplit) {
  const size_t base = ((size_t)blockIdx.x * 256 + threadIdx.x) * 8;
  const int b = (int)(base >> 20);
  const int d0 = (int)(base & 255);
  float sum[8] = {};
  for (int s = 0; s < nsplit; ++s) {
    bf16x8 v = *(const bf16x8*)&opart[(size_t)s * (4u << 20) + base];
#pragma unroll
    for (int j = 0; j < 8; ++j) sum[j] += (float)v[j];
  }
  bf16x8 v0 = *(const bf16x8*)&Vb[((size_t)b << 20) + d0];
  float4 o0, o1;
  o0.x = sum[0] + (float)v0[0] * (1.0f / 4096.0f);
  o0.y = sum[1] + (float)v0[1] * (1.0f / 4096.0f);
  o0.z = sum[2] + (float)v0[2] * (1.0f / 4096.0f);
  o0.w = sum[3] + (float)v0[3] * (1.0f / 4096.0f);
  o1.x = sum[4] + (float)v0[4] * (1.0f / 4096.0f);
  o1.y = sum[5] + (float)v0[5] * (1.0f / 4096.0f);
  o1.z = sum[6] + (float)v0[6] * (1.0f / 4096.0f);
  o1.w = sum[7] + (float)v0[7] * (1.0f / 4096.0f);
  *(float4*)&out[base] = o0;
  *(float4*)&out[base + 4] = o1;
}

// ---------------------------------------------------------------- launch
extern "C" void kernel_launch(void* const* d_in, const int* in_sizes, int n_in,
                              void* d_out, int out_size, void* d_ws, size_t ws_size,
                              hipStream_t stream) {
  const float* x = (const float*)d_in[0];
  const float* Wq = (const float*)d_in[1];
  const float* Wk = (const float*)d_in[2];
  const float* Wv = (const float*)d_in[3];
  float* out = (float*)d_out;
  char* ws = (char*)d_ws;
  __bf16* Qb = (__bf16*)(ws);                             // 8 MB
  __bf16* Kb = (__bf16*)(ws + (8u << 20));                // 8 MB
  __bf16* Vb = (__bf16*)(ws + (16u << 20));               // 8 MB
  __bf16* VpT = (__bf16*)(ws + (24u << 20));              // 8 MB (blocked)
  float* colsum = (float*)(ws + (32u << 20));             // 64 KB
  __bf16* Wb = (__bf16*)(ws + (32u << 20) + (1u << 16));  // 384 KB
  const size_t base = (32u << 20) + (1u << 16) + (384u << 10);
  __bf16* opart = (__bf16*)(ws + base);                   // 8 MB per split
  int nsplit = 1;
  if (ws_size >= base + 4u * (8u << 20)) nsplit = 4;
  else if (ws_size >= base + 2u * (8u << 20)) nsplit = 2;
  const int fuse = (nsplit == 1);

  k_prep<<<dim3(768), dim3(256), 0, stream>>>(Wq, Wk, Wv, Wb, colsum);
  k_qkv<<<dim3(256), dim3(256), 0, stream>>>(x, Wb, Qb, Kb, Vb);
  k_colsum<<<dim3(512), dim3(256), 0, stream>>>(Qb, Kb, colsum);
  k_vpt<<<dim3(64, 4, 4), dim3(256), 0, stream>>>(Vb, colsum, VpT);
  k_attn<<<dim3(256 * nsplit), dim3(256), 0, stream>>>(Qb, Kb, VpT, Vb, opart, out,
                                                       nsplit, fuse);
  if (!fuse)
    k_final<<<dim3(2048), dim3(256), 0, stream>>>(opart, Vb, out, nsplit);
}

// Round 7
// 204.906 us; speedup vs baseline: 1.8100x; 1.0182x over previous
//
#include <hip/hip_runtime.h>
#include <hip/hip_bf16.h>

// MaskedAttentionLayer: B=4, N=4096, D=256, fp32 in/out.
// mask keeps strictly-future (m>n); softmax over QUERY axis (per-column).
// O = E @ (V/colsum), E = exp(S/16); col m=0 fully masked -> V[b,0,:]/4096.

typedef float f32x4 __attribute__((ext_vector_type(4)));
typedef __bf16 bf16x8 __attribute__((ext_vector_type(8)));
typedef __bf16 bf16x4 __attribute__((ext_vector_type(4)));

#define MFMA16(a, b, c) __builtin_amdgcn_mfma_f32_16x16x32_bf16((a), (b), (c), 0, 0, 0)

constexpr int SEQ = 4096;
constexpr int DIM = 256;

// async global->LDS DMA, 16B/lane (dest = wave-uniform base + lane*16)
__device__ __forceinline__ void gl16(const __bf16* g, __bf16* l) {
  __builtin_amdgcn_global_load_lds((const __attribute__((address_space(1))) void*)g,
                                   (__attribute__((address_space(3))) void*)l, 16, 0, 0);
}

// ---------------------------------------------------------------- k_prep
__global__ void k_prep(const float* __restrict__ Wq, const float* __restrict__ Wk,
                       const float* __restrict__ Wv, __bf16* __restrict__ Wb,
                       float* __restrict__ colsum) {
  int i = blockIdx.x * 256 + threadIdx.x;
  if (i < 3 * 65536) {
    const float* src = (i < 65536) ? Wq : (i < 131072 ? Wk : Wv);
    Wb[i] = (__bf16)src[i & 65535];
  }
  if (i < 4 * SEQ) colsum[i] = 0.f;
}

// ---------------------------------------------------------------- k_qkv
// (r6-verified, unchanged)
__global__ __launch_bounds__(256, 2) void k_qkv(const float* __restrict__ x,
                                                const __bf16* __restrict__ Wb,
                                                __bf16* __restrict__ Qb,
                                                __bf16* __restrict__ Kb,
                                                __bf16* __restrict__ Vb) {
  __shared__ __bf16 wsh[64][264];
  const int t = threadIdx.x, lane = t & 63, w = t >> 6;
  const int ln = lane & 15, quad = lane >> 4, q8 = quad * 8;
  const int i0 = blockIdx.x * 64;
  bf16x8 xa[8];
#pragma unroll
  for (int kf = 0; kf < 8; ++kf) {
    const float* src = &x[(size_t)(i0 + w * 16 + ln) * DIM + kf * 32 + q8];
    float4 v0 = *(const float4*)&src[0];
    float4 v1 = *(const float4*)&src[4];
    xa[kf] = bf16x8{(__bf16)v0.x, (__bf16)v0.y, (__bf16)v0.z, (__bf16)v0.w,
                    (__bf16)v1.x, (__bf16)v1.y, (__bf16)v1.z, (__bf16)v1.w};
  }
  for (int zj = 0; zj < 12; ++zj) {
    const int z = zj >> 2, j0 = (zj & 3) * 64;
    const __bf16* W = Wb + z * 65536 + j0 * 256;
    bf16x8 stg[8];
#pragma unroll
    for (int i = 0; i < 8; ++i) stg[i] = *(const bf16x8*)&W[(t + i * 256) * 8];
    __syncthreads();
#pragma unroll
    for (int i = 0; i < 8; ++i)
      *(bf16x8*)&wsh[(t >> 5) + i * 8][(t & 31) * 8] = stg[i];
    __syncthreads();
    f32x4 acc[4] = {};
#pragma unroll
    for (int kf = 0; kf < 8; ++kf) {
      bf16x8 bb[4];
#pragma unroll
      for (int tj = 0; tj < 4; ++tj)
        bb[tj] = *(bf16x8*)&wsh[tj * 16 + ln][kf * 32 + q8];
#pragma unroll
      for (int tj = 0; tj < 4; ++tj) acc[tj] = MFMA16(xa[kf], bb[tj], acc[tj]);
    }
    __bf16* Out = (z == 0) ? Qb : (z == 1 ? Kb : Vb);
#pragma unroll
    for (int tj = 0; tj < 4; ++tj)
#pragma unroll
      for (int r = 0; r < 4; ++r) {
        int row = i0 + w * 16 + quad * 4 + r;
        int col = j0 + tj * 16 + ln;
        Out[(size_t)row * DIM + col] = (__bf16)acc[tj][r];
      }
  }
}

// ---------------------------------------------------------------- k_colsum v7
// colsum[b,m] = sum_{n<m} exp(q_n.k_m/16). 1024 blocks x 256 thr (2/CU).
// Block owns m-tile 64: wave w owns 16 m-cols, K B-frags in 64 VGPRs.
// Q chunks (64n x 256) staged via XOR-swizzled global_load_lds, double-
// buffered (2x32KB), ONE barrier per step: stage(i+1) issued at top of
// step i -> a full step of latency hiding. Per-lane column ownership:
// lane's m = m0+16w+ln for ALL its acc entries -> scalar csum + 2 shuffles.
__global__ __launch_bounds__(256, 2) void k_colsum(const __bf16* __restrict__ Qb,
                                                   const __bf16* __restrict__ Kb,
                                                   float* __restrict__ colsum) {
  __shared__ __bf16 qsh[2 * 64 * 256];  // 64 KB, two 32KB buffers
  const int t = threadIdx.x, lane = t & 63, w = t >> 6;
  const int ln = lane & 15, quad = lane >> 4, q8 = quad * 8;
  const int bid = blockIdx.x;
  const int b = (bid & 7) >> 1;                 // XCD-pair pinned batch
  const int i = ((bid >> 3) << 1) | (bid & 1);  // 0..255
  const int round = i >> 6, k = i & 63;
  const int mt = (round & 1) ? 63 - k : k;      // reversal balances CU pairs
  const int s = round;                          // n-chunk split 0..3
  const int m0 = mt * 64;
  const __bf16* Qp = Qb + (size_t)b * SEQ * DIM;
  const __bf16* Kp = Kb + (size_t)b * SEQ * DIM;
  // K B-frags: wave's 16 m-cols, full K=256. 64 VGPRs.
  bf16x8 kb[8];
#pragma unroll
  for (int kf = 0; kf < 8; ++kf)
    kb[kf] = *(const bf16x8*)&Kp[(size_t)(m0 + w * 16 + ln) * DIM + kf * 32 + q8];
  auto stageq = [&](int ncv, int buf) {
    const __bf16* src = Qp + (size_t)ncv * 16384;
#pragma unroll
    for (int i2 = 0; i2 < 8; ++i2) {
      int sl = t + i2 * 256;  // 2048 16B slots
      int row = sl >> 5, g = sl & 31;
      gl16(&src[row * 256 + ((g ^ (row & 15)) << 3)], &qsh[buf * 16384 + sl * 8]);
    }
  };
  float csum = 0.f;
  int nc = s, cur = 0;
  if (nc <= mt) stageq(nc, 0);
  for (; nc <= mt; nc += 4, cur ^= 1) {
    __syncthreads();  // drains cur's staging (issued a full step ago)
    if (nc + 4 <= mt) stageq(nc + 4, cur ^ 1);
    f32x4 acc[4] = {};
#pragma unroll
    for (int kf = 0; kf < 8; ++kf) {
#pragma unroll
      for (int tn = 0; tn < 4; ++tn) {
        int row = tn * 16 + ln;
        bf16x8 af = *(const bf16x8*)&qsh[cur * 16384 + row * 256 +
                                         (((kf * 4 + quad) ^ ln) << 3)];
        acc[tn] = MFMA16(af, kb[kf], acc[tn]);
      }
    }
    const int m_g = m0 + w * 16 + ln;
#pragma unroll
    for (int tn = 0; tn < 4; ++tn)
#pragma unroll
      for (int r = 0; r < 4; ++r) {
        int n_g = nc * 64 + tn * 16 + quad * 4 + r;
        if (n_g < m_g) csum += __expf(acc[tn][r] * 0.0625f);
      }
  }
  csum += __shfl_xor(csum, 16);
  csum += __shfl_xor(csum, 32);
  if (quad == 0) atomicAdd(&colsum[b * SEQ + m0 + w * 16 + ln], csum);
}

// ---------------------------------------------------------------- k_vpt
// (r5-verified, unchanged) VpTblk[b][mblk64][d][mloc] = V/colsum.
__global__ void k_vpt(const __bf16* __restrict__ Vb, const float* __restrict__ colsum,
                      __bf16* __restrict__ VpT) {
  __shared__ __bf16 tile[64][72];
  const int t = threadIdx.x;
  const int b = blockIdx.z;
  const int m0 = blockIdx.x * 64, d0 = blockIdx.y * 64;
  {
    int row = t >> 2, part = t & 3;
    float cs = colsum[b * SEQ + m0 + row];
    float inv = (m0 + row == 0) ? (1.0f / 4096.0f) : (1.0f / cs);
#pragma unroll
    for (int i = 0; i < 2; ++i) {
      int c = part * 2 + i;
      bf16x8 v = *(const bf16x8*)&Vb[(size_t)(b * SEQ + m0 + row) * DIM + d0 + c * 8];
      bf16x8 o;
#pragma unroll
      for (int j = 0; j < 8; ++j) o[j] = (__bf16)((float)v[j] * inv);
      *(bf16x8*)&tile[row][c * 8] = o;
    }
  }
  __syncthreads();
  {
    int row = t >> 2, part = t & 3;
#pragma unroll
    for (int i = 0; i < 2; ++i) {
      int c = part * 2 + i;
      bf16x8 o;
#pragma unroll
      for (int j = 0; j < 8; ++j) o[j] = tile[c * 8 + j][row];
      *(bf16x8*)&VpT[(size_t)((b * 64 + blockIdx.x) * 256 + d0 + row) * 64 + c * 8] = o;
    }
  }
}

// ---------------------------------------------------------------- k_attn v7
// (r6-verified, unchanged) 256*nsplit blocks x 256 thr, n-tile 64, m-step 64.
__global__ __launch_bounds__(256, 2) void k_attn(const __bf16* __restrict__ Qb,
                                                 const __bf16* __restrict__ Kb,
                                                 const __bf16* __restrict__ Vt_blk,
                                                 const __bf16* __restrict__ Vb,
                                                 __bf16* __restrict__ opart,
                                                 float* __restrict__ out_f32,
                                                 int nsplit, int fuse) {
  __shared__ __bf16 ksh[64 * 256];  // 32768 B, XOR-swizzled groups
  __shared__ __bf16 vsm[256 * 64];  // 32768 B, XOR-swizzled groups
  __shared__ __bf16 ps[64 * 72];    //  9216 B (pad 8)
  const int t = threadIdx.x, lane = t & 63, w = t >> 6;
  const int ln = lane & 15, quad = lane >> 4, q8 = quad * 8;
  const int wn = w & 1;   // n-half (32 rows) both phases
  const int wm = w >> 1;  // S: m-half (32 cols); PV: d-half (128 cols)
  const int bid = blockIdx.x;
  const int b = (bid & 7) >> 1;                 // XCD-pair pinned batch
  const int i = ((bid >> 3) << 1) | (bid & 1);  // 0..32*nsplit-1
  int nt, s;
  if (nsplit == 1) {
    nt = i & 63; s = 0;
  } else {  // rounds of 64, odd rounds reversed
    int round = i >> 6, k = i & 63;
    nt = (round & 1) ? 63 - k : k;
    s = round;
  }
  const int n0 = nt * 64;
  const __bf16* Qp = Qb + (size_t)b * SEQ * DIM;
  const __bf16* Kp = Kb + (size_t)b * SEQ * DIM;
  const __bf16* Vt = Vt_blk + (size_t)b * SEQ * DIM;  // [64][256][64] blocked
  bf16x8 qf[2][8];
#pragma unroll
  for (int tn = 0; tn < 2; ++tn)
#pragma unroll
    for (int kf = 0; kf < 8; ++kf)
      qf[tn][kf] = *(const bf16x8*)&Qp[(size_t)(n0 + wn * 32 + tn * 16 + ln) * DIM + kf * 32 + q8];
  auto stageK = [&](int msv) {
    const __bf16* kp = Kp + (size_t)msv * 16384;
#pragma unroll
    for (int i2 = 0; i2 < 8; ++i2) {
      int sl = t + i2 * 256;
      int row = sl >> 5, g = sl & 31;
      gl16(&kp[row * 256 + ((g ^ (row & 15)) << 3)], &ksh[sl * 8]);
    }
  };
  auto stageV = [&](int msv) {
    const __bf16* vp = Vt + (size_t)msv * 16384;
#pragma unroll
    for (int i2 = 0; i2 < 8; ++i2) {
      int sl = t + i2 * 256;
      int d = sl >> 3, g = sl & 7;
      gl16(&vp[d * 64 + ((g ^ (d & 7)) << 3)], &vsm[sl * 8]);
    }
  };
  f32x4 accO[2][8] = {};  // [tn][td]
  const int msEnd = nt;
  int ms = 63 - s;
  if (ms >= msEnd) { stageK(ms); stageV(ms); }
  __syncthreads();
  for (; ms >= msEnd; ms -= nsplit) {
    const int msn = ms - nsplit;
    // ---- S phase: wave computes 32n x 32m, K from swizzled ksh
    f32x4 accS[2][2] = {};
#pragma unroll
    for (int kf = 0; kf < 8; ++kf) {
      bf16x8 bb[2];
#pragma unroll
      for (int tm = 0; tm < 2; ++tm) {
        int row = wm * 32 + tm * 16 + ln;
        bb[tm] = *(const bf16x8*)&ksh[row * 256 + (((kf * 4 + quad) ^ ln) << 3)];
      }
#pragma unroll
      for (int tn = 0; tn < 2; ++tn)
#pragma unroll
        for (int tm = 0; tm < 2; ++tm)
          accS[tn][tm] = MFMA16(qf[tn][kf], bb[tm], accS[tn][tm]);
    }
    __syncthreads();  // B0: all ksh reads done
    if (msn >= msEnd) stageK(msn);  // flies over exp+B1+PV
    // mask + exp -> ps [64 n][72]
#pragma unroll
    for (int tn = 0; tn < 2; ++tn)
#pragma unroll
      for (int tm = 0; tm < 2; ++tm) {
        int ml = wm * 32 + tm * 16 + ln;
        int m_g = ms * 64 + ml;
#pragma unroll
        for (int r = 0; r < 4; ++r) {
          int nl = wn * 32 + tn * 16 + quad * 4 + r;
          float e = (n0 + nl >= m_g) ? 0.f : __expf(accS[tn][tm][r] * 0.0625f);
          ps[nl * 72 + ml] = (__bf16)e;
        }
      }
    __syncthreads();  // B1: ps visible (also drains stageK)
    // ---- PV: O[n][d] += P[n][m] * VpT[d][m], V from swizzled vsm
#pragma unroll
    for (int kf = 0; kf < 2; ++kf) {
      bf16x8 aa[2];
#pragma unroll
      for (int tn = 0; tn < 2; ++tn)
        aa[tn] = *(const bf16x8*)&ps[(wn * 32 + tn * 16 + ln) * 72 + kf * 32 + q8];
#pragma unroll
      for (int td = 0; td < 8; ++td) {
        int d = wm * 128 + td * 16 + ln;
        bf16x8 bb = *(const bf16x8*)&vsm[d * 64 + (((kf * 4 + quad) ^ (ln & 7)) << 3)];
#pragma unroll
        for (int tn = 0; tn < 2; ++tn) accO[tn][td] = MFMA16(aa[tn], bb, accO[tn][td]);
      }
    }
    __syncthreads();  // B2: vsm/ps reads done
    if (msn >= msEnd) stageV(msn);
    __syncthreads();  // B3: staged tiles visible (drains gl16s)
  }
  // ---- epilogue
  if (fuse) {
    const __bf16* V0 = Vb + (size_t)b * SEQ * DIM;
    float* Op = out_f32 + (size_t)b * SEQ * DIM;
#pragma unroll
    for (int tn = 0; tn < 2; ++tn)
#pragma unroll
      for (int td = 0; td < 8; ++td) {
        int col = wm * 128 + td * 16 + ln;
        float c0 = (float)V0[col] * (1.0f / 4096.0f);
#pragma unroll
        for (int r = 0; r < 4; ++r) {
          int row = n0 + wn * 32 + tn * 16 + quad * 4 + r;
          Op[(size_t)row * DIM + col] = accO[tn][td][r] + c0;
        }
      }
  } else {
    __bf16* P = opart + (size_t)s * (4u << 20) + ((size_t)b << 20);
#pragma unroll
    for (int tn = 0; tn < 2; ++tn)
#pragma unroll
      for (int td = 0; td < 8; ++td) {
        int col = wm * 128 + td * 16 + ln;
#pragma unroll
        for (int r = 0; r < 4; ++r) {
          int row = n0 + wn * 32 + tn * 16 + quad * 4 + r;
          P[(size_t)row * DIM + col] = (__bf16)accO[tn][td][r];
        }
      }
  }
}

// ---------------------------------------------------------------- k_final
__global__ void k_final(const __bf16* __restrict__ opart, const __bf16* __restrict__ Vb,
                        float* __restrict__ out, int nsplit) {
  const size_t base = ((size_t)blockIdx.x * 256 + threadIdx.x) * 8;
  const int b = (int)(base >> 20);
  const int d0 = (int)(base & 255);
  float sum[8] = {};
  for (int s = 0; s < nsplit; ++s) {
    bf16x8 v = *(const bf16x8*)&opart[(size_t)s * (4u << 20) + base];
#pragma unroll
    for (int j = 0; j < 8; ++j) sum[j] += (float)v[j];
  }
  bf16x8 v0 = *(const bf16x8*)&Vb[((size_t)b << 20) + d0];
  float4 o0, o1;
  o0.x = sum[0] + (float)v0[0] * (1.0f / 4096.0f);
  o0.y = sum[1] + (float)v0[1] * (1.0f / 4096.0f);
  o0.z = sum[2] + (float)v0[2] * (1.0f / 4096.0f);
  o0.w = sum[3] + (float)v0[3] * (1.0f / 4096.0f);
  o1.x = sum[4] + (float)v0[4] * (1.0f / 4096.0f);
  o1.y = sum[5] + (float)v0[5] * (1.0f / 4096.0f);
  o1.z = sum[6] + (float)v0[6] * (1.0f / 4096.0f);
  o1.w = sum[7] + (float)v0[7] * (1.0f / 4096.0f);
  *(float4*)&out[base] = o0;
  *(float4*)&out[base + 4] = o1;
}

// ---------------------------------------------------------------- launch
extern "C" void kernel_launch(void* const* d_in, const int* in_sizes, int n_in,
                              void* d_out, int out_size, void* d_ws, size_t ws_size,
                              hipStream_t stream) {
  const float* x = (const float*)d_in[0];
  const float* Wq = (const float*)d_in[1];
  const float* Wk = (const float*)d_in[2];
  const float* Wv = (const float*)d_in[3];
  float* out = (float*)d_out;
  char* ws = (char*)d_ws;
  __bf16* Qb = (__bf16*)(ws);                             // 8 MB
  __bf16* Kb = (__bf16*)(ws + (8u << 20));                // 8 MB
  __bf16* Vb = (__bf16*)(ws + (16u << 20));               // 8 MB
  __bf16* VpT = (__bf16*)(ws + (24u << 20));              // 8 MB (blocked)
  float* colsum = (float*)(ws + (32u << 20));             // 64 KB
  __bf16* Wb = (__bf16*)(ws + (32u << 20) + (1u << 16));  // 384 KB
  const size_t base = (32u << 20) + (1u << 16) + (384u << 10);
  __bf16* opart = (__bf16*)(ws + base);                   // 8 MB per split
  int nsplit = 1;
  if (ws_size >= base + 4u * (8u << 20)) nsplit = 4;
  else if (ws_size >= base + 2u * (8u << 20)) nsplit = 2;
  const int fuse = (nsplit == 1);

  k_prep<<<dim3(768), dim3(256), 0, stream>>>(Wq, Wk, Wv, Wb, colsum);
  k_qkv<<<dim3(256), dim3(256), 0, stream>>>(x, Wb, Qb, Kb, Vb);
  k_colsum<<<dim3(1024), dim3(256), 0, stream>>>(Qb, Kb, colsum);
  k_vpt<<<dim3(64, 4, 4), dim3(256), 0, stream>>>(Vb, colsum, VpT);
  k_attn<<<dim3(256 * nsplit), dim3(256), 0, stream>>>(Qb, Kb, VpT, Vb, opart, out,
                                                       nsplit, fuse);
  if (!fuse)
    k_final<<<dim3(2048), dim3(256), 0, stream>>>(opart, Vb, out, nsplit);
}